// Round 6
// baseline (305.334 us; speedup 1.0000x reference)
//
#include <hip/hip_runtime.h>

// CharAttention: only row x_end_idx[b,w] survives the gather -> compute only
// that row, with q folded through Wk and Wv folded through Wproj (prep kernel):
//   M_h[c'][c] = 0.25 * sum_d Wq[c'][16h+d] * Wk[c][16h+d]     (2x32x32)
//   N_h[c][i]  =        sum_d Wv[c][16h+d]  * Wproj[16h+d][i]  (2x32x32)
//   rk[h][c]   = sum_c' x[qidx][c'] * M_h[c'][c]
//   s[h][j]    = x[j] . rk[h]  (j<=qidx); e = exp(s)  (no max-sub, |s| small)
//   y[h][c]    = (sum_j e[h][j] x[j][c]) / sum_j e[h][j]
//   out[i]     = x[qidx][i] + sum_{h,c} y[h][c] * N_h[c][i]
//
// R5 lesson (dur unchanged vs R4): bottleneck is per-problem ISSUE SLOTS:
// ~100 DS ops + ~75 VMEM ops per problem (~937 cyc/problem/CU). This round:
//   - 8 consecutive problems per wave -> Mreg/Nreg (64 VMEM) amortized 8x,
//   - all LDS traffic widened to b64/b128 (xs stride 36 = 16B-aligned rows,
//     rk interleaved [c][h] pairs, es read as float4) -> ~63 DS ops/problem.

#define CB      24
#define CC      32
#define DD      16
#define THREEC  96
#define NBW     (512 * 128)
#define WPB     4
#define PPW     8               // problems per wave (consecutive bids)
#define XSS     36              // xs row stride: 144 B, 16B-aligned rows

struct __align__(16) WaveSmem {
    float xs[CB][XSS];          // staged x rows (3456 B)
    float rki[CC][2];           // rk interleaved [c][h] (256 B)
    float es[CB][2];            // e[j][h] pairs; masked j -> 0 (192 B)
    float ys[2][CC];            // normalized y[h][c] (256 B)
};                              // 4160 B -> 4 waves = 16640 B/block

__device__ __forceinline__ void wave_fence() {
    __asm__ volatile("s_waitcnt lgkmcnt(0)" ::: "memory");
}

// ---- prep: M[2][32][32] then N[2][32][32] into ws (16 KB) ----
__global__ void prep_kernel(const float* __restrict__ w_attn,
                            const float* __restrict__ w_proj,
                            float* __restrict__ ws)
{
    const int t = blockIdx.x * 256 + threadIdx.x;   // 0..4095
    if (t < 2048) {                                  // M[h][c'][c]
        const int h = t >> 10, rem = t & 1023, cp = rem >> 5, c = rem & 31;
        float a = 0.f;
        #pragma unroll
        for (int d = 0; d < DD; ++d)
            a = fmaf(w_attn[cp * THREEC + 16 * h + d],
                     w_attn[c * THREEC + CC + 16 * h + d], a);
        ws[t] = a * 0.25f;                           // fold 1/sqrt(D)
    } else {                                         // N[h][c][i]
        const int u = t - 2048;
        const int h = u >> 10, rem = u & 1023, c = rem >> 5, i = rem & 31;
        float a = 0.f;
        #pragma unroll
        for (int d = 0; d < DD; ++d)
            a = fmaf(w_attn[c * THREEC + 2 * CC + 16 * h + d],
                     w_proj[(16 * h + d) * CC + i], a);
        ws[t] = a;
    }
}

__global__ __launch_bounds__(256, 4) void char_attn_kernel(
    const float* __restrict__ x,        // [B*W, 24, 32]
    const int*   __restrict__ xend,     // [B*W]
    const float* __restrict__ ws,       // M[2][32][32], N[2][32][32]
    float*       __restrict__ out)      // [B*W, 32]
{
    __shared__ WaveSmem sm[WPB];

    const int tid  = threadIdx.x;
    const int lane = tid & 63;
    const int wave = tid >> 6;
    WaveSmem& S = sm[wave];

    const int i32  = lane & 31;
    const int half = lane >> 5;
    const int wid  = blockIdx.x * WPB + wave;    // 0..8191
    const int pbase = wid * PPW;                 // 8 consecutive problems

    const float* Mw = ws;                        // [2][32][32]
    const float* Nw = ws + 2048;                 // [2][32][32]

    // ---- fused weights in registers, loaded ONCE per wave (8x amortized) ----
    float Mreg[CC];                              // M[half][c'][i32]
    #pragma unroll
    for (int cp = 0; cp < CC; ++cp)
        Mreg[cp] = Mw[(half * CC + cp) * CC + i32];
    float Nreg[2][DD];                           // N[h][half*16+k][i32]
    #pragma unroll
    for (int h = 0; h < 2; ++h)
        #pragma unroll
        for (int k = 0; k < DD; ++k)
            Nreg[h][k] = Nw[(h * CC + half * DD + k) * CC + i32];

    #pragma unroll 1
    for (int pi = 0; pi < PPW; ++pi) {
        const int bid  = pbase + pi;
        const int qidx = xend[bid];              // wave-uniform scalar load
        const int L    = qidx + 1;
        const float* xb = x + (size_t)bid * (CB * CC);

        // ---- P0: stage x rows 0..qidx (coalesced float2; 2-way banks) ----
        {
            const float2* xb2 = (const float2*)xb;
            const int n2 = L * (CC / 2);         // <= 384 -> <= 6 iters
            for (int t = lane; t < n2; t += 64) {
                float2 v = xb2[t];
                const int r = t >> 4, c = (t & 15) * 2;
                *(float2*)&S.xs[r][c] = v;
            }
        }
        wave_fence();

        // ---- P1: rk[half][i32] = xs[qidx] . Mreg  (8 b128 broadcast) ----
        {
            const float4* xr = (const float4*)&S.xs[qidx][0];   // 16B-aligned
            float a0 = 0.f, a1 = 0.f;
            #pragma unroll
            for (int t = 0; t < 8; ++t) {
                float4 xv = xr[t];
                a0 = fmaf(xv.x, Mreg[4 * t + 0], a0);
                a1 = fmaf(xv.y, Mreg[4 * t + 1], a1);
                a0 = fmaf(xv.z, Mreg[4 * t + 2], a0);
                a1 = fmaf(xv.w, Mreg[4 * t + 3], a1);
            }
            S.rki[i32][half] = a0 + a1;          // interleaved [c][h]
        }
        wave_fence();

        // ---- P2: scores (c split across halves) + exp -> es[j] pair ----
        {
            float s0 = 0.f, s1 = 0.f;
            if (i32 <= qidx) {                   // j = i32
                const int cb = half * DD;
                const float4* xr = (const float4*)&S.xs[i32][cb];  // 4 b128
                const float4* rp = (const float4*)&S.rki[cb][0];   // 8 b128
                #pragma unroll
                for (int t = 0; t < 4; ++t) {
                    float4 xv = xr[t];
                    float4 r01 = rp[2 * t];      // (rk0[c],rk1[c],rk0[c+1],rk1[c+1])
                    float4 r23 = rp[2 * t + 1];  // (rk0[c+2],rk1[c+2],...)
                    s0 = fmaf(xv.x, r01.x, s0);  s1 = fmaf(xv.x, r01.y, s1);
                    s0 = fmaf(xv.y, r01.z, s0);  s1 = fmaf(xv.y, r01.w, s1);
                    s0 = fmaf(xv.z, r23.x, s0);  s1 = fmaf(xv.z, r23.y, s1);
                    s0 = fmaf(xv.w, r23.z, s0);  s1 = fmaf(xv.w, r23.w, s1);
                }
            }
            s0 += __shfl_xor(s0, 32);
            s1 += __shfl_xor(s1, 32);
            // no max-subtraction: s ~ N(0,1), fp32 exp safe (validated R5)
            const float e0 = (i32 <= qidx) ? __expf(s0) : 0.f;
            const float e1 = (i32 <= qidx) ? __expf(s1) : 0.f;
            if (half == 0 && i32 < CB)
                *(float2*)&S.es[i32][0] = make_float2(e0, e1);
        }
        wave_fence();

        // ---- P3: y + prob-sums, j split across halves; es via float4 ----
        {
            float y0 = 0.f, y1 = 0.f, p0 = 0.f, p1 = 0.f;
            #pragma unroll
            for (int k = 0; k < 6; ++k) {        // 2 j's per float4 read
                const int j0 = half * 12 + 2 * k;
                float4 eq = *(const float4*)&S.es[j0][0];   // 16B-aligned
                const int r0 = (j0     <= qidx) ? j0     : qidx;
                const int r1 = (j0 + 1 <= qidx) ? j0 + 1 : qidx;
                float xv0 = S.xs[r0][i32];       // distinct, conflict-free
                float xv1 = S.xs[r1][i32];
                y0 = fmaf(eq.x, xv0, y0);  y1 = fmaf(eq.y, xv0, y1);
                p0 += eq.x;                p1 += eq.y;
                y0 = fmaf(eq.z, xv1, y0);  y1 = fmaf(eq.w, xv1, y1);
                p0 += eq.z;                p1 += eq.w;
            }
            y0 += __shfl_xor(y0, 32);
            y1 += __shfl_xor(y1, 32);
            p0 += __shfl_xor(p0, 32);
            p1 += __shfl_xor(p1, 32);
            if (half == 0) S.ys[0][i32] = y0 / p0;   // head 0
            else           S.ys[1][i32] = y1 / p1;   // head 1
        }
        wave_fence();

        // ---- P4: out = residual + sum_{h,c} y[h][c] * Nreg[h][c] ----
        {
            const float4* y0p = (const float4*)&S.ys[0][half * DD];
            const float4* y1p = (const float4*)&S.ys[1][half * DD];
            float a0 = 0.f, a1 = 0.f;
            #pragma unroll
            for (int t = 0; t < 4; ++t) {
                float4 u = y0p[t], w = y1p[t];
                a0 = fmaf(u.x, Nreg[0][4 * t + 0], a0);
                a1 = fmaf(w.x, Nreg[1][4 * t + 0], a1);
                a0 = fmaf(u.y, Nreg[0][4 * t + 1], a0);
                a1 = fmaf(w.y, Nreg[1][4 * t + 1], a1);
                a0 = fmaf(u.z, Nreg[0][4 * t + 2], a0);
                a1 = fmaf(w.z, Nreg[1][4 * t + 2], a1);
                a0 = fmaf(u.w, Nreg[0][4 * t + 3], a0);
                a1 = fmaf(w.w, Nreg[1][4 * t + 3], a1);
            }
            float a = a0 + a1;
            a += __shfl_xor(a, 32);
            if (half == 0)
                out[(size_t)bid * CC + i32] = a + S.xs[qidx][i32];
        }
        wave_fence();                            // LDS reused next problem
    }
}

extern "C" void kernel_launch(void* const* d_in, const int* in_sizes, int n_in,
                              void* d_out, int out_size, void* d_ws, size_t ws_size,
                              hipStream_t stream) {
    const float* x      = (const float*)d_in[0];
    const int*   xend   = (const int*)d_in[1];
    const float* w_attn = (const float*)d_in[2];
    const float* w_proj = (const float*)d_in[3];
    float* out = (float*)d_out;
    float* ws  = (float*)d_ws;                   // 16 KB used

    prep_kernel<<<dim3(16), dim3(256), 0, stream>>>(w_attn, w_proj, ws);
    char_attn_kernel<<<dim3(NBW / (WPB * PPW)), dim3(WPB * 64), 0, stream>>>(
        x, xend, ws, out);
}